// Round 1
// baseline (1460.633 us; speedup 1.0000x reference)
//
#include <hip/hip_runtime.h>

typedef unsigned short u16;
typedef __bf16 bf16x8 __attribute__((ext_vector_type(8)));
typedef float f32x4 __attribute__((ext_vector_type(4)));

#define HN 128
#define TM 64
#define ASTRIDE 136   // 128 + 8 pad, keeps rows 16B-aligned, spreads banks

__device__ __forceinline__ u16 f2bf(float f) {
  union { float f; unsigned u; } v; v.f = f;
  unsigned r = v.u + 0x7fffu + ((v.u >> 16) & 1u);
  return (u16)(r >> 16);
}
__device__ __forceinline__ float bf2f(u16 v) {
  union { unsigned u; float f; } x; x.u = ((unsigned)v) << 16; return x.f;
}
__device__ __forceinline__ float silu_f(float x) { return x / (1.f + __expf(-x)); }

// ---- pack weights into MFMA B-fragment layout: P[kg][n][8], kg=k/8 ----
// mats per layer: 0=msgW1a 1=msgW1b 2=msgW2 3=nodeW1a 4=nodeW1b 5=nodeW2
__global__ void pack_weights(const float* __restrict__ msg_w1, const float* __restrict__ msg_w2,
                             const float* __restrict__ node_w1, const float* __restrict__ node_w2,
                             u16* __restrict__ pw) {
  int id = blockIdx.x * 256 + threadIdx.x;
  if (id >= 4 * 6 * 16384) return;
  int l = id / (6 * 16384);
  int rem = id % (6 * 16384);
  int m = rem / 16384;
  int e = rem % 16384;
  int kg = e >> 10;
  int n = (e >> 3) & 127;
  int j = e & 7;
  int k = kg * 8 + j;
  float v = 0.f;
  switch (m) {
    case 0: v = msg_w1[(l * 257 + k) * 128 + n]; break;
    case 1: v = msg_w1[(l * 257 + 128 + k) * 128 + n]; break;
    case 2: v = msg_w2[(l * 128 + k) * 128 + n]; break;
    case 3: v = node_w1[(l * 256 + k) * 128 + n]; break;
    case 4: v = node_w1[(l * 256 + 128 + k) * 128 + n]; break;
    case 5: v = node_w2[(l * 128 + k) * 128 + n]; break;
  }
  pw[id] = f2bf(v);
}

__global__ void embed_kernel(const float* __restrict__ x, const float* __restrict__ emb_w,
                             const float* __restrict__ emb_b, u16* __restrict__ h, int N) {
  int id = blockIdx.x * 256 + threadIdx.x;
  if (id >= N * HN) return;
  int n = id >> 7, c = id & 127;
  h[id] = f2bf(x[n] * emb_w[c] + emb_b[c]);
}

__global__ void dist_kernel(const int* __restrict__ eidx, const float* __restrict__ pos,
                            float* __restrict__ dist, int E) {
  int e = blockIdx.x * 256 + threadIdx.x;
  if (e >= E) return;
  int r = eidx[e], c = eidx[E + e];
  float dx = pos[r * 3 + 0] - pos[c * 3 + 0];
  float dy = pos[r * 3 + 1] - pos[c * 3 + 1];
  float dz = pos[r * 3 + 2] - pos[c * 3 + 2];
  dist[e] = dx * dx + dy * dy + dz * dz;
}

__device__ __forceinline__ void gemm64(const u16* s_A, const u16* s_W,
                                       int w, int quad, int m16, f32x4 acc[8]) {
#pragma unroll
  for (int ks = 0; ks < 4; ks++) {
    bf16x8 a = *(const bf16x8*)&s_A[(w * 16 + m16) * ASTRIDE + ks * 32 + quad * 8];
#pragma unroll
    for (int ct = 0; ct < 8; ct++) {
      bf16x8 b = *(const bf16x8*)&s_W[(ks * 4 + quad) * 1024 + (ct * 16 + m16) * 8];
      acc[ct] = __builtin_amdgcn_mfma_f32_16x16x32_bf16(a, b, acc[ct], 0, 0, 0);
    }
  }
}

// Fused 2-layer MLP over a 64-row tile. EDGE: gather x_i/x_j via indices,
// +dist rank-1 term, scatter-atomic to aggr. NODE: direct rows [h | aggr],
// store h_new (bf16).
template <bool EDGE>
__global__ __launch_bounds__(256) void mlp_kernel(
    const u16* __restrict__ hbf, const float* __restrict__ aggr_in,
    float* __restrict__ aggr_out, u16* __restrict__ hout,
    const u16* __restrict__ pw, const float* __restrict__ w1d,
    const float* __restrict__ b1, const float* __restrict__ b2,
    const int* __restrict__ eidx, const float* __restrict__ dist,
    int nrows, int nnodes) {
  __shared__ __align__(16) u16 s_A[TM * ASTRIDE];
  __shared__ __align__(16) u16 s_W[16384];
  __shared__ int s_r0[TM];
  __shared__ int s_r1[TM];
  __shared__ float s_dist[TM];

  const int t = threadIdx.x;
  const int w = t >> 6;
  const int lane = t & 63;
  const int quad = lane >> 4;
  const int m16 = lane & 15;
  const int tile0 = blockIdx.x * TM;

  if (EDGE) {
    if (t < TM) {
      int e = tile0 + t;
      bool v = (e < nrows);
      s_r0[t] = v ? eidx[nrows + e] : 0;  // col = target i
      s_r1[t] = v ? eidx[e] : 0;          // row = source j
      s_dist[t] = v ? dist[e] : 0.f;
    }
    __syncthreads();
  }

  // ---------- stage 1: W1a, A = h[col] (edge) / h rows (node) ----------
  {
    const int4* src = (const int4*)pw;
    int4* dst = (int4*)s_W;
#pragma unroll
    for (int i = 0; i < 8; i++) dst[t + i * 256] = src[t + i * 256];
  }
  {
    int r = t >> 2;
    int qo = (t & 3) * 32;
    int node;
    if (EDGE) node = s_r0[r];
    else { node = tile0 + r; if (node >= nnodes) node = nnodes - 1; }
    const int4* src = (const int4*)(hbf + node * HN + qo);
    int4* dst = (int4*)(s_A + r * ASTRIDE + qo);
#pragma unroll
    for (int i = 0; i < 4; i++) dst[i] = src[i];
  }
  __syncthreads();

  f32x4 zero4 = {0.f, 0.f, 0.f, 0.f};
  f32x4 acc[8];
#pragma unroll
  for (int ct = 0; ct < 8; ct++) acc[ct] = zero4;

  gemm64(s_A, s_W, w, quad, m16, acc);
  __syncthreads();

  // ---------- stage 2: W1b, A = h[row] (edge) / aggr rows (node) ----------
  {
    const int4* src = (const int4*)(pw + 16384);
    int4* dst = (int4*)s_W;
#pragma unroll
    for (int i = 0; i < 8; i++) dst[t + i * 256] = src[t + i * 256];
  }
  if (EDGE) {
    int r = t >> 2;
    int qo = (t & 3) * 32;
    int node = s_r1[r];
    const int4* src = (const int4*)(hbf + node * HN + qo);
    int4* dst = (int4*)(s_A + r * ASTRIDE + qo);
#pragma unroll
    for (int i = 0; i < 4; i++) dst[i] = src[i];
  } else {
    int r = t >> 2;
    int qo = (t & 3) * 32;
    int node = tile0 + r; if (node >= nnodes) node = nnodes - 1;
    const float4* src = (const float4*)(aggr_in + node * HN + qo);
    u16* dst = s_A + r * ASTRIDE + qo;
#pragma unroll
    for (int i = 0; i < 8; i++) {
      float4 v = src[i];
      ushort4 o;
      o.x = f2bf(v.x); o.y = f2bf(v.y); o.z = f2bf(v.z); o.w = f2bf(v.w);
      *(ushort4*)(dst + i * 4) = o;
    }
  }
  __syncthreads();

  gemm64(s_A, s_W, w, quad, m16, acc);
  __syncthreads();  // protects s_A (hidden write) and s_W (W2 load)

  // ---------- epilogue 1: bias (+dist*w1d), silu -> hidden into s_A; load W2 ----------
  {
    const int4* src = (const int4*)(pw + 32768);
    int4* dst = (int4*)s_W;
#pragma unroll
    for (int i = 0; i < 8; i++) dst[t + i * 256] = src[t + i * 256];
  }
  {
    float bb1[8];
#pragma unroll
    for (int ct = 0; ct < 8; ct++) bb1[ct] = b1[ct * 16 + m16];
    if (EDGE) {
      float wd[8];
#pragma unroll
      for (int ct = 0; ct < 8; ct++) wd[ct] = w1d[ct * 16 + m16];
#pragma unroll
      for (int ct = 0; ct < 8; ct++)
#pragma unroll
        for (int j = 0; j < 4; j++) {
          int row = w * 16 + quad * 4 + j;
          float xv = acc[ct][j] + bb1[ct] + s_dist[row] * wd[ct];
          s_A[row * ASTRIDE + ct * 16 + m16] = f2bf(silu_f(xv));
        }
    } else {
#pragma unroll
      for (int ct = 0; ct < 8; ct++)
#pragma unroll
        for (int j = 0; j < 4; j++) {
          int row = w * 16 + quad * 4 + j;
          float xv = acc[ct][j] + bb1[ct];
          s_A[row * ASTRIDE + ct * 16 + m16] = f2bf(silu_f(xv));
        }
    }
  }
  __syncthreads();

  // ---------- GEMM2 + epilogue 2 ----------
#pragma unroll
  for (int ct = 0; ct < 8; ct++) acc[ct] = zero4;
  gemm64(s_A, s_W, w, quad, m16, acc);

  float bb2[8];
#pragma unroll
  for (int ct = 0; ct < 8; ct++) bb2[ct] = b2[ct * 16 + m16];

  if (EDGE) {
#pragma unroll
    for (int ct = 0; ct < 8; ct++)
#pragma unroll
      for (int j = 0; j < 4; j++) {
        int row = w * 16 + quad * 4 + j;
        if (tile0 + row < nrows) {
          int tgt = s_r0[row];
          atomicAdd(&aggr_out[tgt * HN + ct * 16 + m16], acc[ct][j] + bb2[ct]);
        }
      }
  } else {
#pragma unroll
    for (int ct = 0; ct < 8; ct++)
#pragma unroll
      for (int j = 0; j < 4; j++) {
        int row = w * 16 + quad * 4 + j;
        int n = tile0 + row;
        if (n < nrows) hout[n * HN + ct * 16 + m16] = f2bf(acc[ct][j] + bb2[ct]);
      }
  }
}

// batch is sorted -> per-block running sums, atomic only at segment boundaries
__global__ void pool_kernel(const u16* __restrict__ h, const int* __restrict__ batch,
                            float* __restrict__ g, int N) {
  int c = threadIdx.x;  // 128
  int base = blockIdx.x * 256;
  int cur = -1;
  float sum = 0.f;
  for (int i = 0; i < 256; i++) {
    int n = base + i;
    if (n >= N) break;
    int b = batch[n];
    if (b != cur) {
      if (cur >= 0) atomicAdd(&g[cur * HN + c], sum);
      cur = b; sum = 0.f;
    }
    sum += bf2f(h[n * HN + c]);
  }
  if (cur >= 0) atomicAdd(&g[cur * HN + c], sum);
}

__global__ void out_kernel(const float* __restrict__ g, const float* __restrict__ w1,
                           const float* __restrict__ b1, const float* __restrict__ w2,
                           const float* __restrict__ b2, float* __restrict__ out) {
  int gi = threadIdx.x;  // 64
  float s[32];
#pragma unroll
  for (int c = 0; c < 32; c++) s[c] = b1[c];
  for (int k = 0; k < 128; k++) {
    float gv = g[gi * HN + k];
#pragma unroll
    for (int c = 0; c < 32; c++) s[c] += gv * w1[k * 32 + c];
  }
  float acc = b2[0];
#pragma unroll
  for (int c = 0; c < 32; c++) acc += silu_f(s[c]) * w2[c];
  out[gi] = acc;
}

extern "C" void kernel_launch(void* const* d_in, const int* in_sizes, int n_in,
                              void* d_out, int out_size, void* d_ws, size_t ws_size,
                              hipStream_t stream) {
  const float* x = (const float*)d_in[0];
  const float* pos = (const float*)d_in[1];
  const int* eidx = (const int*)d_in[2];
  const int* batch = (const int*)d_in[3];
  const float* emb_w = (const float*)d_in[4];
  const float* emb_b = (const float*)d_in[5];
  const float* msg_w1 = (const float*)d_in[6];
  const float* msg_b1 = (const float*)d_in[7];
  const float* msg_w2 = (const float*)d_in[8];
  const float* msg_b2 = (const float*)d_in[9];
  const float* node_w1 = (const float*)d_in[10];
  const float* node_b1 = (const float*)d_in[11];
  const float* node_w2 = (const float*)d_in[12];
  const float* node_b2 = (const float*)d_in[13];
  const float* out_w1 = (const float*)d_in[14];
  const float* out_b1 = (const float*)d_in[15];
  const float* out_w2 = (const float*)d_in[16];
  const float* out_b2 = (const float*)d_in[17];
  float* outp = (float*)d_out;

  const int N = 30000, E = 600000, G = 64;

  u16* hA = (u16*)d_ws;                       // N*128 bf16
  u16* hB = hA + (size_t)N * HN;              // N*128 bf16
  float* aggr = (float*)(hB + (size_t)N * HN);  // N*128 f32
  float* ddist = aggr + (size_t)N * HN;       // E f32
  float* g = ddist + E;                       // 64*128 f32
  u16* pw = (u16*)(g + G * HN);               // 4*6*16384 bf16

  pack_weights<<<(4 * 6 * 16384 + 255) / 256, 256, 0, stream>>>(msg_w1, msg_w2, node_w1, node_w2, pw);
  embed_kernel<<<(N * HN + 255) / 256, 256, 0, stream>>>(x, emb_w, emb_b, hA, N);
  dist_kernel<<<(E + 255) / 256, 256, 0, stream>>>(eidx, pos, ddist, E);

  u16* hcur = hA;
  u16* hnext = hB;
  for (int l = 0; l < 4; l++) {
    hipMemsetAsync(aggr, 0, (size_t)N * HN * sizeof(float), stream);
    mlp_kernel<true><<<(E + TM - 1) / TM, 256, 0, stream>>>(
        hcur, nullptr, aggr, nullptr,
        pw + (size_t)(l * 6 + 0) * 16384,
        msg_w1 + (size_t)(l * 257 + 256) * 128,  // w1d row
        msg_b1 + l * 128, msg_b2 + l * 128,
        eidx, ddist, E, N);
    mlp_kernel<false><<<(N + TM - 1) / TM, 256, 0, stream>>>(
        hcur, aggr, nullptr, hnext,
        pw + (size_t)(l * 6 + 3) * 16384,
        nullptr,
        node_b1 + l * 128, node_b2 + l * 128,
        nullptr, nullptr, N, N);
    u16* tmp = hcur; hcur = hnext; hnext = tmp;
  }

  hipMemsetAsync(g, 0, (size_t)G * HN * sizeof(float), stream);
  pool_kernel<<<(N + 255) / 256, 128, 0, stream>>>(hcur, batch, g, N);
  out_kernel<<<1, 64, 0, stream>>>(g, out_w1, out_b1, out_w2, out_b2, outp);
}

// Round 2
// 795.078 us; speedup vs baseline: 1.8371x; 1.8371x over previous
//
#include <hip/hip_runtime.h>

typedef unsigned short u16;
typedef __bf16 bf16x8 __attribute__((ext_vector_type(8)));
typedef float f32x4 __attribute__((ext_vector_type(4)));

#define HN 128
#define TM 64
#define ASTRIDE 136   // 128 + 8 pad (u16), rows 16B-aligned

__device__ __forceinline__ u16 f2bf(float f) {
  union { float f; unsigned u; } v; v.f = f;
  unsigned r = v.u + 0x7fffu + ((v.u >> 16) & 1u);
  return (u16)(r >> 16);
}
__device__ __forceinline__ float bf2f(u16 v) {
  union { unsigned u; float f; } x; x.u = ((unsigned)v) << 16; return x.f;
}
__device__ __forceinline__ float silu_f(float x) { return x / (1.f + __expf(-x)); }

// ---- pack weights into MFMA B-fragment layout: P[kg][n][8], kg=k/8 ----
// mats per layer: 0=msgW1a 1=msgW1b 2=msgW2 3=nodeW1a 4=nodeW1b 5=nodeW2
__global__ void pack_weights(const float* __restrict__ msg_w1, const float* __restrict__ msg_w2,
                             const float* __restrict__ node_w1, const float* __restrict__ node_w2,
                             u16* __restrict__ pw) {
  int id = blockIdx.x * 256 + threadIdx.x;
  if (id >= 4 * 6 * 16384) return;
  int l = id / (6 * 16384);
  int rem = id % (6 * 16384);
  int m = rem / 16384;
  int e = rem % 16384;
  int kg = e >> 10;
  int n = (e >> 3) & 127;
  int j = e & 7;
  int k = kg * 8 + j;
  float v = 0.f;
  switch (m) {
    case 0: v = msg_w1[(l * 257 + k) * 128 + n]; break;
    case 1: v = msg_w1[(l * 257 + 128 + k) * 128 + n]; break;
    case 2: v = msg_w2[(l * 128 + k) * 128 + n]; break;
    case 3: v = node_w1[(l * 256 + k) * 128 + n]; break;
    case 4: v = node_w1[(l * 256 + 128 + k) * 128 + n]; break;
    case 5: v = node_w2[(l * 128 + k) * 128 + n]; break;
  }
  pw[id] = f2bf(v);
}

__global__ void embed_kernel(const float* __restrict__ x, const float* __restrict__ emb_w,
                             const float* __restrict__ emb_b, u16* __restrict__ h, int N) {
  int id = blockIdx.x * 256 + threadIdx.x;
  if (id >= N * HN) return;
  int n = id >> 7, c = id & 127;
  h[id] = f2bf(x[n] * emb_w[c] + emb_b[c]);
}

__global__ void dist_kernel(const int* __restrict__ eidx, const float* __restrict__ pos,
                            float* __restrict__ dist, int E) {
  int e = blockIdx.x * 256 + threadIdx.x;
  if (e >= E) return;
  int r = eidx[e], c = eidx[E + e];
  float dx = pos[r * 3 + 0] - pos[c * 3 + 0];
  float dy = pos[r * 3 + 1] - pos[c * 3 + 1];
  float dz = pos[r * 3 + 2] - pos[c * 3 + 2];
  dist[e] = dx * dx + dy * dy + dz * dz;
}

// ---- counting sort of edges by target ----
__global__ void hist_kernel(const int* __restrict__ eidx, int* __restrict__ deg, int E_) {
  int e = blockIdx.x * 256 + threadIdx.x;
  if (e < E_) atomicAdd(&deg[eidx[E_ + e]], 1);
}

__global__ void scan1_kernel(const int* __restrict__ deg, int* __restrict__ off,
                             int* __restrict__ bsum, int n) {
  __shared__ int s[256];
  int t = threadIdx.x;
  int i = blockIdx.x * 256 + t;
  int v = (i < n) ? deg[i] : 0;
  s[t] = v;
  for (int d = 1; d < 256; d <<= 1) {
    __syncthreads();
    int x = (t >= d) ? s[t - d] : 0;
    __syncthreads();
    s[t] += x;
  }
  __syncthreads();
  if (i < n) off[i] = s[t] - v;
  if (t == 255) bsum[blockIdx.x] = s[255];
}

__global__ void scan2_kernel(int* __restrict__ bsum, int nb) {
  __shared__ int s[256];
  int t = threadIdx.x;
  int v = (t < nb) ? bsum[t] : 0;
  s[t] = v;
  for (int d = 1; d < 256; d <<= 1) {
    __syncthreads();
    int x = (t >= d) ? s[t - d] : 0;
    __syncthreads();
    s[t] += x;
  }
  __syncthreads();
  if (t < nb) bsum[t] = s[t] - v;  // exclusive block offsets
}

__global__ void scan3_kernel(int* __restrict__ off, const int* __restrict__ bsum,
                             int* __restrict__ cursor, int n) {
  int i = blockIdx.x * 256 + threadIdx.x;
  if (i < n) {
    int v = off[i] + bsum[blockIdx.x];
    off[i] = v;
    cursor[i] = v;
  }
}

__global__ void scatter_kernel(const int* __restrict__ eidx, const float* __restrict__ ddist,
                               int* __restrict__ cursor, int* __restrict__ es_src,
                               int* __restrict__ es_tgt, float* __restrict__ es_dist, int E_) {
  int e = blockIdx.x * 256 + threadIdx.x;
  if (e >= E_) return;
  int tg = eidx[E_ + e];
  int p = atomicAdd(&cursor[tg], 1);
  es_src[p] = eidx[e];
  es_tgt[p] = tg;
  es_dist[p] = ddist[e];
}

__device__ __forceinline__ void gemm64(const u16* s_A, const u16* s_W,
                                       int w, int quad, int m16, f32x4 acc[8]) {
#pragma unroll
  for (int ks = 0; ks < 4; ks++) {
    bf16x8 a = *(const bf16x8*)&s_A[(w * 16 + m16) * ASTRIDE + ks * 32 + quad * 8];
#pragma unroll
    for (int ct = 0; ct < 8; ct++) {
      bf16x8 b = *(const bf16x8*)&s_W[(ks * 4 + quad) * 1024 + (ct * 16 + m16) * 8];
      acc[ct] = __builtin_amdgcn_mfma_f32_16x16x32_bf16(a, b, acc[ct], 0, 0, 0);
    }
  }
}

// ---- per-node projections: P = h@W1a + b1, Q = h@W1b (both bf16) ----
__global__ __launch_bounds__(256) void proj_kernel(
    const u16* __restrict__ hbf, u16* __restrict__ Pout, u16* __restrict__ Qout,
    const u16* __restrict__ pw, const float* __restrict__ b1, int nnodes) {
  __shared__ __align__(16) u16 s_A[TM * ASTRIDE];
  __shared__ __align__(16) u16 s_W[16384];
  const int t = threadIdx.x;
  const int w = t >> 6, lane = t & 63, quad = lane >> 4, m16 = lane & 15;
  const int tile0 = blockIdx.x * TM;
  {
    int r = t >> 2, qo = (t & 3) * 32;
    int node = tile0 + r;
    if (node >= nnodes) node = nnodes - 1;
    const int4* src = (const int4*)(hbf + node * HN + qo);
    int4* dst = (int4*)(s_A + r * ASTRIDE + qo);
#pragma unroll
    for (int i = 0; i < 4; i++) dst[i] = src[i];
  }
  {
    const int4* src = (const int4*)pw;
    int4* dst = (int4*)s_W;
#pragma unroll
    for (int i = 0; i < 8; i++) dst[t + i * 256] = src[t + i * 256];
  }
  __syncthreads();
  f32x4 acc[8];
#pragma unroll
  for (int ct = 0; ct < 8; ct++) acc[ct] = {0.f, 0.f, 0.f, 0.f};
  gemm64(s_A, s_W, w, quad, m16, acc);
  __syncthreads();
  {
    const int4* src = (const int4*)(pw + 16384);
    int4* dst = (int4*)s_W;
#pragma unroll
    for (int i = 0; i < 8; i++) dst[t + i * 256] = src[t + i * 256];
  }
  float bb[8];
#pragma unroll
  for (int ct = 0; ct < 8; ct++) bb[ct] = b1[ct * 16 + m16];
#pragma unroll
  for (int ct = 0; ct < 8; ct++)
#pragma unroll
    for (int j = 0; j < 4; j++) {
      int n = tile0 + w * 16 + quad * 4 + j;
      if (n < nnodes) Pout[n * HN + ct * 16 + m16] = f2bf(acc[ct][j] + bb[ct]);
    }
  __syncthreads();
#pragma unroll
  for (int ct = 0; ct < 8; ct++) acc[ct] = {0.f, 0.f, 0.f, 0.f};
  gemm64(s_A, s_W, w, quad, m16, acc);
#pragma unroll
  for (int ct = 0; ct < 8; ct++)
#pragma unroll
    for (int j = 0; j < 4; j++) {
      int n = tile0 + w * 16 + quad * 4 + j;
      if (n < nnodes) Qout[n * HN + ct * 16 + m16] = f2bf(acc[ct][j]);
    }
}

// ---- edge kernel: hidden = silu(P[tgt]+Q[src]+d*w1d); GEMM2; segmented
// reduce by (sorted) target; atomicAdd per segment ----
__global__ __launch_bounds__(256) void edge_kernel(
    const u16* __restrict__ P, const u16* __restrict__ Q,
    float* __restrict__ aggr, const u16* __restrict__ pw2,
    const float* __restrict__ w1d, const float* __restrict__ b2,
    const int* __restrict__ es_src, const int* __restrict__ es_tgt,
    const float* __restrict__ es_dist, int E_) {
  __shared__ __align__(16) char smem[17408 + 32768];  // s_A | s_W ; s_out overlays
  __shared__ int s_tgt[TM];
  __shared__ int s_src[TM];
  __shared__ float s_dist[TM];
  u16* s_A = (u16*)smem;
  u16* s_W = (u16*)(smem + 17408);
  float* s_out = (float*)smem;  // 64 x 132 fp32 = 33792 B

  const int t = threadIdx.x;
  const int w = t >> 6, lane = t & 63, quad = lane >> 4, m16 = lane & 15;
  const int tile0 = blockIdx.x * TM;

  if (t < TM) {
    int e = tile0 + t;
    bool v = e < E_;
    s_tgt[t] = v ? es_tgt[e] : -1;
    s_src[t] = v ? es_src[e] : 0;
    s_dist[t] = v ? es_dist[e] : 0.f;
  }
  {
    const int4* src = (const int4*)pw2;
    int4* dst = (int4*)s_W;
#pragma unroll
    for (int i = 0; i < 8; i++) dst[t + i * 256] = src[t + i * 256];
  }
  __syncthreads();

  // gather + elementwise silu -> s_A (bf16)
  {
    int r = t >> 2;
    int qo = (t & 3) * 32;
    int tg = s_tgt[r]; if (tg < 0) tg = 0;
    int sr = s_src[r];
    float dr = s_dist[r];
    const int4* pP = (const int4*)(P + tg * HN + qo);
    const int4* pQ = (const int4*)(Q + sr * HN + qo);
    const float4* pw1d = (const float4*)(w1d + qo);
    u16* dst = s_A + r * ASTRIDE + qo;
#pragma unroll
    for (int i = 0; i < 4; i++) {
      int4 pv = pP[i];
      int4 qv = pQ[i];
      float4 wa = pw1d[i * 2 + 0];
      float4 wb = pw1d[i * 2 + 1];
      const u16* pu = (const u16*)&pv;
      const u16* qu = (const u16*)&qv;
      float wv[8] = {wa.x, wa.y, wa.z, wa.w, wb.x, wb.y, wb.z, wb.w};
      u16 o[8];
#pragma unroll
      for (int j2 = 0; j2 < 8; j2++) {
        float v = bf2f(pu[j2]) + bf2f(qu[j2]) + dr * wv[j2];
        o[j2] = f2bf(silu_f(v));
      }
      *(int4*)(dst + i * 8) = *(int4*)o;
    }
  }
  __syncthreads();

  f32x4 acc[8];
#pragma unroll
  for (int ct = 0; ct < 8; ct++) acc[ct] = {0.f, 0.f, 0.f, 0.f};
  gemm64(s_A, s_W, w, quad, m16, acc);
  __syncthreads();  // all s_A/s_W reads done before s_out overlay write

  float bb2[8];
#pragma unroll
  for (int ct = 0; ct < 8; ct++) bb2[ct] = b2[ct * 16 + m16];
#pragma unroll
  for (int ct = 0; ct < 8; ct++)
#pragma unroll
    for (int j = 0; j < 4; j++) {
      int row = w * 16 + quad * 4 + j;
      s_out[row * 132 + ct * 16 + m16] = acc[ct][j] + bb2[ct];
    }
  __syncthreads();

  // segmented reduce over sorted targets: 2 halves x 128 cols
  int c = t & 127, half = t >> 7;
  int r0 = half * 32;
  int cur = s_tgt[r0];
  float sum = 0.f;
#pragma unroll 4
  for (int r = r0; r < r0 + 32; r++) {
    int tg = s_tgt[r];
    if (tg != cur) {
      if (cur >= 0) atomicAdd(&aggr[cur * HN + c], sum);
      cur = tg;
      sum = 0.f;
    }
    sum += s_out[r * 132 + c];
  }
  if (cur >= 0) atomicAdd(&aggr[cur * HN + c], sum);
}

// ---- node MLP: h' = silu([h|aggr]@W1 + b1)@W2 + b2 ----
__global__ __launch_bounds__(256) void node_kernel(
    const u16* __restrict__ hbf, const float* __restrict__ aggr_in,
    u16* __restrict__ hout, const u16* __restrict__ pw,
    const float* __restrict__ b1, const float* __restrict__ b2, int nnodes) {
  __shared__ __align__(16) u16 s_A[TM * ASTRIDE];
  __shared__ __align__(16) u16 s_W[16384];
  const int t = threadIdx.x;
  const int w = t >> 6, lane = t & 63, quad = lane >> 4, m16 = lane & 15;
  const int tile0 = blockIdx.x * TM;

  {
    const int4* src = (const int4*)pw;
    int4* dst = (int4*)s_W;
#pragma unroll
    for (int i = 0; i < 8; i++) dst[t + i * 256] = src[t + i * 256];
  }
  {
    int r = t >> 2, qo = (t & 3) * 32;
    int node = tile0 + r;
    if (node >= nnodes) node = nnodes - 1;
    const int4* src = (const int4*)(hbf + node * HN + qo);
    int4* dst = (int4*)(s_A + r * ASTRIDE + qo);
#pragma unroll
    for (int i = 0; i < 4; i++) dst[i] = src[i];
  }
  __syncthreads();

  f32x4 acc[8];
#pragma unroll
  for (int ct = 0; ct < 8; ct++) acc[ct] = {0.f, 0.f, 0.f, 0.f};
  gemm64(s_A, s_W, w, quad, m16, acc);
  __syncthreads();

  {
    const int4* src = (const int4*)(pw + 16384);
    int4* dst = (int4*)s_W;
#pragma unroll
    for (int i = 0; i < 8; i++) dst[t + i * 256] = src[t + i * 256];
  }
  {
    int r = t >> 2, qo = (t & 3) * 32;
    int node = tile0 + r;
    if (node >= nnodes) node = nnodes - 1;
    const float4* src = (const float4*)(aggr_in + node * HN + qo);
    u16* dst = s_A + r * ASTRIDE + qo;
#pragma unroll
    for (int i = 0; i < 8; i++) {
      float4 v = src[i];
      ushort4 o;
      o.x = f2bf(v.x); o.y = f2bf(v.y); o.z = f2bf(v.z); o.w = f2bf(v.w);
      *(ushort4*)(dst + i * 4) = o;
    }
  }
  __syncthreads();
  gemm64(s_A, s_W, w, quad, m16, acc);
  __syncthreads();

  {
    const int4* src = (const int4*)(pw + 32768);
    int4* dst = (int4*)s_W;
#pragma unroll
    for (int i = 0; i < 8; i++) dst[t + i * 256] = src[t + i * 256];
  }
  {
    float bb1[8];
#pragma unroll
    for (int ct = 0; ct < 8; ct++) bb1[ct] = b1[ct * 16 + m16];
#pragma unroll
    for (int ct = 0; ct < 8; ct++)
#pragma unroll
      for (int j = 0; j < 4; j++) {
        int row = w * 16 + quad * 4 + j;
        float xv = acc[ct][j] + bb1[ct];
        s_A[row * ASTRIDE + ct * 16 + m16] = f2bf(silu_f(xv));
      }
  }
  __syncthreads();

#pragma unroll
  for (int ct = 0; ct < 8; ct++) acc[ct] = {0.f, 0.f, 0.f, 0.f};
  gemm64(s_A, s_W, w, quad, m16, acc);

  float bb2[8];
#pragma unroll
  for (int ct = 0; ct < 8; ct++) bb2[ct] = b2[ct * 16 + m16];
#pragma unroll
  for (int ct = 0; ct < 8; ct++)
#pragma unroll
    for (int j = 0; j < 4; j++) {
      int row = w * 16 + quad * 4 + j;
      int n = tile0 + row;
      if (n < nnodes) hout[n * HN + ct * 16 + m16] = f2bf(acc[ct][j] + bb2[ct]);
    }
}

// batch sorted -> per-block running sums, atomic only at segment boundaries
__global__ void pool_kernel(const u16* __restrict__ h, const int* __restrict__ batch,
                            float* __restrict__ g, int N) {
  int c = threadIdx.x;  // 128
  int base = blockIdx.x * 256;
  int cur = -1;
  float sum = 0.f;
  for (int i = 0; i < 256; i++) {
    int n = base + i;
    if (n >= N) break;
    int b = batch[n];
    if (b != cur) {
      if (cur >= 0) atomicAdd(&g[cur * HN + c], sum);
      cur = b; sum = 0.f;
    }
    sum += bf2f(h[n * HN + c]);
  }
  if (cur >= 0) atomicAdd(&g[cur * HN + c], sum);
}

__global__ void out_kernel(const float* __restrict__ g, const float* __restrict__ w1,
                           const float* __restrict__ b1, const float* __restrict__ w2,
                           const float* __restrict__ b2, float* __restrict__ out) {
  int gi = threadIdx.x;  // 64
  float s[32];
#pragma unroll
  for (int c = 0; c < 32; c++) s[c] = b1[c];
  for (int k = 0; k < 128; k++) {
    float gv = g[gi * HN + k];
#pragma unroll
    for (int c = 0; c < 32; c++) s[c] += gv * w1[k * 32 + c];
  }
  float acc = b2[0];
#pragma unroll
  for (int c = 0; c < 32; c++) acc += silu_f(s[c]) * w2[c];
  out[gi] = acc;
}

extern "C" void kernel_launch(void* const* d_in, const int* in_sizes, int n_in,
                              void* d_out, int out_size, void* d_ws, size_t ws_size,
                              hipStream_t stream) {
  const float* x = (const float*)d_in[0];
  const float* pos = (const float*)d_in[1];
  const int* eidx = (const int*)d_in[2];
  const int* batch = (const int*)d_in[3];
  const float* emb_w = (const float*)d_in[4];
  const float* emb_b = (const float*)d_in[5];
  const float* msg_w1 = (const float*)d_in[6];
  const float* msg_b1 = (const float*)d_in[7];
  const float* msg_w2 = (const float*)d_in[8];
  const float* msg_b2 = (const float*)d_in[9];
  const float* node_w1 = (const float*)d_in[10];
  const float* node_b1 = (const float*)d_in[11];
  const float* node_w2 = (const float*)d_in[12];
  const float* node_b2 = (const float*)d_in[13];
  const float* out_w1 = (const float*)d_in[14];
  const float* out_b1 = (const float*)d_in[15];
  const float* out_w2 = (const float*)d_in[16];
  const float* out_b2 = (const float*)d_in[17];
  float* outp = (float*)d_out;

  const int N = 30000, E = 600000, G = 64;
  const size_t NH = (size_t)N * HN;

  u16* hA = (u16*)d_ws;                       // N*128 bf16
  u16* hB = hA + NH;                          // N*128 bf16
  u16* Pp = hB + NH;                          // N*128 bf16
  u16* Qp = Pp + NH;                          // N*128 bf16
  float* aggr = (float*)(Qp + NH);            // N*128 f32
  float* ddist = aggr + NH;                   // E f32
  int* es_src = (int*)(ddist + E);            // E
  int* es_tgt = es_src + E;                   // E
  float* es_dist = (float*)(es_tgt + E);      // E
  int* deg = (int*)(es_dist + E);             // N
  int* off = deg + N;                         // N
  int* cursor = off + N;                      // N
  int* bsum = cursor + N;                     // 128
  float* g = (float*)(bsum + 128);            // 64*128 f32
  u16* pw = (u16*)(g + G * HN);               // 4*6*16384 bf16

  const int NB = (N + 255) / 256;  // 118 scan blocks

  pack_weights<<<(4 * 6 * 16384 + 255) / 256, 256, 0, stream>>>(msg_w1, msg_w2, node_w1, node_w2, pw);
  embed_kernel<<<(N * HN + 255) / 256, 256, 0, stream>>>(x, emb_w, emb_b, hA, N);
  dist_kernel<<<(E + 255) / 256, 256, 0, stream>>>(eidx, pos, ddist, E);

  // counting sort by target
  hipMemsetAsync(deg, 0, N * sizeof(int), stream);
  hist_kernel<<<(E + 255) / 256, 256, 0, stream>>>(eidx, deg, E);
  scan1_kernel<<<NB, 256, 0, stream>>>(deg, off, bsum, N);
  scan2_kernel<<<1, 256, 0, stream>>>(bsum, NB);
  scan3_kernel<<<NB, 256, 0, stream>>>(off, bsum, cursor, N);
  scatter_kernel<<<(E + 255) / 256, 256, 0, stream>>>(eidx, ddist, cursor, es_src, es_tgt, es_dist, E);

  u16* hcur = hA;
  u16* hnext = hB;
  for (int l = 0; l < 4; l++) {
    const u16* pwl = pw + (size_t)(l * 6) * 16384;
    proj_kernel<<<(N + TM - 1) / TM, 256, 0, stream>>>(
        hcur, Pp, Qp, pwl, msg_b1 + l * 128, N);
    hipMemsetAsync(aggr, 0, NH * sizeof(float), stream);
    edge_kernel<<<(E + TM - 1) / TM, 256, 0, stream>>>(
        Pp, Qp, aggr, pwl + 2 * 16384,
        msg_w1 + (size_t)(l * 257 + 256) * 128,  // w1d row
        msg_b2 + l * 128, es_src, es_tgt, es_dist, E);
    node_kernel<<<(N + TM - 1) / TM, 256, 0, stream>>>(
        hcur, aggr, hnext, pwl + 3 * 16384,
        node_b1 + l * 128, node_b2 + l * 128, N);
    u16* tmp = hcur; hcur = hnext; hnext = tmp;
  }

  hipMemsetAsync(g, 0, (size_t)G * HN * sizeof(float), stream);
  pool_kernel<<<(N + 255) / 256, 128, 0, stream>>>(hcur, batch, g, N);
  out_kernel<<<1, 64, 0, stream>>>(g, out_w1, out_b1, out_w2, out_b2, outp);
}